// Round 9
// baseline (301.348 us; speedup 1.0000x reference)
//
#include <hip/hip_runtime.h>

#define ALPHA 0.2f
#define EPS 1e-16f

static constexpr int F_IN = 256;
static constexpr int F_OUT = 128;
static constexpr int HEADS = 4;
static constexpr int COLS = HEADS * F_OUT; // 512

typedef __bf16 bf16x8 __attribute__((ext_vector_type(8)));
typedef float f32x4 __attribute__((ext_vector_type(4)));

static __device__ __forceinline__ unsigned short f2bf(float f) {
  unsigned int u = __float_as_uint(f);
  unsigned int r = (u + 0x7FFFu + ((u >> 16) & 1u)) >> 16;  // RN-even
  return (unsigned short)r;
}
static __device__ __forceinline__ float bf_lo(unsigned int u) {
  return __uint_as_float(u << 16);
}
static __device__ __forceinline__ float bf_hi(unsigned int u) {
  return __uint_as_float(u & 0xFFFF0000u);
}

// ---------------- K0: W cast to bf16 ------------------------------------------
__global__ __launch_bounds__(256) void k_wcast(const float* __restrict__ W,
                                               unsigned short* __restrict__ Wb) {
  const int i = blockIdx.x * 256 + threadIdx.x;   // 512*256/4 = 32768 float4s
  const float4 v = ((const float4*)W)[i];
  ((ushort4*)Wb)[i] = make_ushort4(f2bf(v.x), f2bf(v.y), f2bf(v.z), f2bf(v.w));
}

// ---------------- K1: edge rank (for atomic-free scatter) ---------------------
__global__ void k_rank(const int* __restrict__ src, int* __restrict__ cnt,
                       unsigned short* __restrict__ rank, int E) {
  int i = blockIdx.x * blockDim.x + threadIdx.x;
  const int stride = gridDim.x * blockDim.x;
  for (; i < E; i += stride) rank[i] = (unsigned short)atomicAdd(&cnt[src[i]], 1);
}

// ---------------- K2: 128x128 MFMA GEMM (f32 A, cast-in-staging) --------------
// + fused score epilogue (this block == head bx) + int8(excess-128) quant.
// rec[n] (32B): bytes 0..15 = sdst (4 f32); bytes 16..31 = 8 bf16 scales.
// Hq row layout (per 64-col block b): u32 at byte 64b+4k holds cols {0,16,32,48}+k.
__global__ __launch_bounds__(256) void k_gemm_q(const float* __restrict__ A,
                                                const unsigned short* __restrict__ B,
                                                unsigned char* __restrict__ Hq,
                                                unsigned char* __restrict__ rec,
                                                float* __restrict__ ssrc,
                                                const float* __restrict__ Av, int N) {
  __shared__ __bf16 As[128][40];
  __shared__ __bf16 Bs[128][40];
  __shared__ float sS[128], sD[128];
  // --- bijective XCD chunking of the 1D grid (col-fastest within chunk) ---
  const int T = gridDim.x;
  const int q8 = T >> 3, r8 = T & 7;
  const int xcd = blockIdx.x & 7, ii = blockIdx.x >> 3;
  const int gp = (xcd < r8) ? xcd * (q8 + 1) + ii
                            : r8 * (q8 + 1) + (xcd - r8) * q8 + ii;
  const int by = gp >> 2;                  // row-tile
  const int bx = gp & 3;                   // 128-col block == head
  const int t = threadIdx.x;
  const int w = t >> 6, l = t & 63;
  const int wr = w >> 1, wc = w & 1;       // 2x2 wave grid, each 64x64
  const int m0 = by << 7, n0 = bx << 7;
  const int lr = t >> 1, seg16 = (t & 1) << 4;   // staging: row 0..127, col 0/16
  f32x4 acc[4][4] = {};
  for (int k0 = 0; k0 < F_IN; k0 += 32) {
    int ar = m0 + lr; if (ar >= N) ar = N - 1;   // clamp; stores guarded
    const float4 f0 = *(const float4*)&A[(size_t)ar * F_IN + k0 + seg16];
    const float4 f1 = *(const float4*)&A[(size_t)ar * F_IN + k0 + seg16 + 4];
    const float4 f2 = *(const float4*)&A[(size_t)ar * F_IN + k0 + seg16 + 8];
    const float4 f3 = *(const float4*)&A[(size_t)ar * F_IN + k0 + seg16 + 12];
    const uint4 b0 = *(const uint4*)&B[(size_t)(n0 + lr) * F_IN + k0 + seg16];
    const uint4 b1 = *(const uint4*)&B[(size_t)(n0 + lr) * F_IN + k0 + seg16 + 8];
    bf16x8 v0, v1;
    v0[0] = (__bf16)f0.x; v0[1] = (__bf16)f0.y; v0[2] = (__bf16)f0.z; v0[3] = (__bf16)f0.w;
    v0[4] = (__bf16)f1.x; v0[5] = (__bf16)f1.y; v0[6] = (__bf16)f1.z; v0[7] = (__bf16)f1.w;
    v1[0] = (__bf16)f2.x; v1[1] = (__bf16)f2.y; v1[2] = (__bf16)f2.z; v1[3] = (__bf16)f2.w;
    v1[4] = (__bf16)f3.x; v1[5] = (__bf16)f3.y; v1[6] = (__bf16)f3.z; v1[7] = (__bf16)f3.w;
    __syncthreads();
    *(bf16x8*)&As[lr][seg16] = v0;  *(bf16x8*)&As[lr][seg16 + 8] = v1;
    *(uint4*)&Bs[lr][seg16] = b0;   *(uint4*)&Bs[lr][seg16 + 8] = b1;
    __syncthreads();
    const int kb = (l >> 4) << 3;
    bf16x8 af[4], bf_[4];
#pragma unroll
    for (int mi = 0; mi < 4; ++mi)
      af[mi] = *(const bf16x8*)&As[(wr << 6) + (mi << 4) + (l & 15)][kb];
#pragma unroll
    for (int ni = 0; ni < 4; ++ni)
      bf_[ni] = *(const bf16x8*)&Bs[(wc << 6) + (ni << 4) + (l & 15)][kb];
#pragma unroll
    for (int mi = 0; mi < 4; ++mi)
#pragma unroll
      for (int ni = 0; ni < 4; ++ni)
        acc[mi][ni] = __builtin_amdgcn_mfma_f32_16x16x32_bf16(af[mi], bf_[ni], acc[mi][ni], 0, 0, 0);
  }
  // ---- score epilogue: s_src/s_dst for head bx from f32 accumulators ----
  {
    float as_[4], ad_[4];
#pragma unroll
    for (int ni = 0; ni < 4; ++ni) {
      const int f = (wc << 6) + (ni << 4) + (l & 15);
      as_[ni] = Av[bx * 256 + f];
      ad_[ni] = Av[bx * 256 + 128 + f];
    }
#pragma unroll
    for (int mi = 0; mi < 4; ++mi)
#pragma unroll
      for (int r = 0; r < 4; ++r) {
        float ds_ = 0.f, dd_ = 0.f;
#pragma unroll
        for (int ni = 0; ni < 4; ++ni) {
          ds_ = fmaf(acc[mi][ni][r], as_[ni], ds_);
          dd_ = fmaf(acc[mi][ni][r], ad_[ni], dd_);
        }
#pragma unroll
        for (int m = 1; m < 16; m <<= 1) {
          ds_ += __shfl_xor(ds_, m);
          dd_ += __shfl_xor(dd_, m);
        }
        if (wc == 0 && (l & 15) == 0) {
          const int rl = (wr << 6) + (mi << 4) + ((l >> 4) << 2) + r;
          sS[rl] = ds_; sD[rl] = dd_;
        }
      }
    __syncthreads();
    if (wc == 1) {
#pragma unroll
      for (int mi = 0; mi < 4; ++mi)
#pragma unroll
        for (int r = 0; r < 4; ++r) {
          float ds_ = 0.f, dd_ = 0.f;
#pragma unroll
          for (int ni = 0; ni < 4; ++ni) {
            ds_ = fmaf(acc[mi][ni][r], as_[ni], ds_);
            dd_ = fmaf(acc[mi][ni][r], ad_[ni], dd_);
          }
#pragma unroll
          for (int m = 1; m < 16; m <<= 1) {
            ds_ += __shfl_xor(ds_, m);
            dd_ += __shfl_xor(dd_, m);
          }
          if ((l & 15) == 0) {
            const int rl = (wr << 6) + (mi << 4) + ((l >> 4) << 2) + r;
            const int row = m0 + rl;
            if (row < N) {
              ssrc[row * 4 + bx] = sS[rl] + ds_;
              *(float*)&rec[(size_t)row * 32 + (bx << 2)] = sD[rl] + dd_;
            }
          }
        }
    }
  }
  // ---- quant epilogue: per-row absmax per 64-col block, excess-128 int8 ----
  const int bxg = (bx << 1) + wc;          // global 64-col block 0..7
#pragma unroll
  for (int mi = 0; mi < 4; ++mi)
#pragma unroll
    for (int r = 0; r < 4; ++r) {
      float mx = 0.f;
#pragma unroll
      for (int ni = 0; ni < 4; ++ni) mx = fmaxf(mx, fabsf(acc[mi][ni][r]));
#pragma unroll
      for (int m = 1; m < 16; m <<= 1) mx = fmaxf(mx, __shfl_xor(mx, m));
      const int row = m0 + (wr << 6) + (mi << 4) + ((l >> 4) << 2) + r;
      if (row < N) {
        const float inv = (mx > 0.f) ? 127.f / mx : 0.f;
        if ((l & 15) == 0)
          *(unsigned short*)&rec[(size_t)row * 32 + 16 + (bxg << 1)] = f2bf(mx * (1.f / 127.f));
        unsigned int pk = 0;
#pragma unroll
        for (int ni = 0; ni < 4; ++ni) {
          float tq = fminf(fmaxf(rintf(acc[mi][ni][r] * inv), -127.f), 127.f);
          pk |= ((unsigned int)(((int)tq + 128) & 255)) << (8 * ni);  // excess-128
        }
        *(unsigned int*)&Hq[(size_t)row * 512 + (bxg << 6) + ((l & 15) << 2)] = pk;
      }
    }
}

// ---------------- scans over cnt -> off ---------------------------------------
__global__ __launch_bounds__(1024) void k_scan1(int* __restrict__ cnt,
                                                int* __restrict__ bsum, int N) {
  __shared__ int ws[16];
  const int t = threadIdx.x, g = blockIdx.x * 1024 + t;
  const int lane = t & 63, w = t >> 6;
  int v = (g < N) ? cnt[g] : 0;
#pragma unroll
  for (int o = 1; o < 64; o <<= 1) {
    const int y = __shfl_up(v, o);
    if (lane >= o) v += y;
  }
  if (lane == 63) ws[w] = v;
  __syncthreads();
  if (w == 0) {
    int s = (lane < 16) ? ws[lane] : 0;
#pragma unroll
    for (int o = 1; o < 16; o <<= 1) {
      const int y = __shfl_up(s, o);
      if (lane >= o) s += y;
    }
    if (lane < 16) ws[lane] = s;
  }
  __syncthreads();
  v += (w > 0) ? ws[w - 1] : 0;
  if (g < N) cnt[g] = v;                  // in-place inclusive within chunk
  if (t == 1023) bsum[blockIdx.x] = v;
}

// fused: every block scans bsum locally (nb <= 256), then adds carry
__global__ __launch_bounds__(1024) void k_scan3(const int* __restrict__ part,
                                                const int* __restrict__ bsum,
                                                int* __restrict__ off, int N, int nb) {
  __shared__ int sbuf[256];
  const int t = threadIdx.x;
  if (t < 64) {
    int carry = 0;
    for (int base = 0; base < nb; base += 64) {
      int v = (base + t < nb) ? bsum[base + t] : 0;
#pragma unroll
      for (int o = 1; o < 64; o <<= 1) {
        const int y = __shfl_up(v, o);
        if (t >= o) v += y;
      }
      v += carry;
      if (base + t < nb) sbuf[base + t] = v;
      carry = __shfl(v, 63);
    }
  }
  __syncthreads();
  const int g = blockIdx.x * 1024 + t;
  if (g == 0) off[0] = 0;
  if (g < N) off[g + 1] = part[g] + (blockIdx.x ? sbuf[blockIdx.x - 1] : 0);
}

// ---------------- K3: scatter (no atomics; u16 dst) ---------------------------
__global__ void k_scatter(const int* __restrict__ src, const int* __restrict__ dst,
                          const int* __restrict__ off, const unsigned short* __restrict__ rank,
                          unsigned short* __restrict__ csr_dst, int E) {
  int i = blockIdx.x * blockDim.x + threadIdx.x;
  const int stride = gridDim.x * blockDim.x;
  for (; i < E; i += stride)
    csr_dst[off[src[i]] + rank[i]] = (unsigned short)dst[i];
}

// ---------------- K4: fused softmax + SpMM, excess-128 int8 -------------------
__global__ __launch_bounds__(256) void k_spmm(const uint2* __restrict__ Hq2,
    const float4* __restrict__ ssrc4, const unsigned char* __restrict__ rec,
    const int* __restrict__ off, const unsigned short* __restrict__ csr_dst,
    const float* __restrict__ bias, float* __restrict__ out, int N) {
  __shared__ float wbuf[4][8][72];   // [wave][col-block][edge], w[h]*scl[d][b]
  __shared__ int   ibuf[4][64];
  const int wv = threadIdx.x >> 6;
  const int lane = threadIdx.x & 63;
  const int n = (blockIdx.x << 2) + wv;
  if (n >= N) return;                 // wave-private LDS, no barriers
  const int hg = lane >> 4;           // head of this lane
  const int b8 = lane >> 3;           // 64-col block of this lane
  const float4 ss4 = ssrc4[n];
  float den4[4] = {};
  float acc[8] = {};
  float sw = 0.f;                     // sum of this lane's scaled weights
  const int beg = off[n], end = off[n + 1];
  for (int c0 = beg; c0 < end; c0 += 64) {
    const int cnt = min(64, end - c0);
    if (lane < cnt) {                 // -------- phase A --------
      const int d = csr_dst[c0 + lane];          // coalesced u16
      ibuf[wv][lane] = d << 6;                   // row base in uint2 units
      const float4 sd4 = *(const float4*)&rec[(size_t)d * 32];       // one line:
      const uint4  sc  = *(const uint4*)&rec[(size_t)d * 32 + 16];   // sdst+scales
      float e0 = ss4.x + sd4.x; e0 = fmaxf(e0, ALPHA * e0);
      float e1 = ss4.y + sd4.y; e1 = fmaxf(e1, ALPHA * e1);
      float e2 = ss4.z + sd4.z; e2 = fmaxf(e2, ALPHA * e2);
      float e3 = ss4.w + sd4.w; e3 = fmaxf(e3, ALPHA * e3);
      const float w0 = __expf(e0), w1 = __expf(e1), w2 = __expf(e2), w3 = __expf(e3);
      den4[0] += w0; den4[1] += w1; den4[2] += w2; den4[3] += w3;
      wbuf[wv][0][lane] = w0 * bf_lo(sc.x); wbuf[wv][1][lane] = w0 * bf_hi(sc.x);
      wbuf[wv][2][lane] = w1 * bf_lo(sc.y); wbuf[wv][3][lane] = w1 * bf_hi(sc.y);
      wbuf[wv][4][lane] = w2 * bf_lo(sc.z); wbuf[wv][5][lane] = w2 * bf_hi(sc.z);
      wbuf[wv][6][lane] = w3 * bf_lo(sc.w); wbuf[wv][7][lane] = w3 * bf_hi(sc.w);
    }
#pragma unroll 8
    for (int j = 0; j < cnt; ++j) {   // -------- phase B --------
      const float wgt = wbuf[wv][b8][j];         // LDS broadcast (scaled)
      const int db = ibuf[wv][j];                // LDS broadcast
      const uint2 q = Hq2[db + lane];            // 8B gather, 512B/row/wave
      sw += wgt;
      acc[0] = fmaf(wgt, (float)(q.x & 0xffu),         acc[0]);
      acc[1] = fmaf(wgt, (float)((q.x >> 8) & 0xffu),  acc[1]);
      acc[2] = fmaf(wgt, (float)((q.x >> 16) & 0xffu), acc[2]);
      acc[3] = fmaf(wgt, (float)(q.x >> 24),           acc[3]);
      acc[4] = fmaf(wgt, (float)(q.y & 0xffu),         acc[4]);
      acc[5] = fmaf(wgt, (float)((q.y >> 8) & 0xffu),  acc[5]);
      acc[6] = fmaf(wgt, (float)((q.y >> 16) & 0xffu), acc[6]);
      acc[7] = fmaf(wgt, (float)(q.y >> 24),           acc[7]);
    }
  }
#pragma unroll
  for (int k = 0; k < 4; ++k)
#pragma unroll
    for (int m = 1; m < 64; m <<= 1) den4[k] += __shfl_xor(den4[k], m);
  const float r = 1.f / (den4[hg] + EPS);
  const float corr = 128.f * sw;      // undo excess-128 bias
#pragma unroll
  for (int i = 0; i < 8; ++i) acc[i] = (acc[i] - corr) * r;
#pragma unroll
  for (int i = 0; i < 8; ++i) {       // sum the 4 heads (same feature at l^16,l^32)
    acc[i] += __shfl_xor(acc[i], 16);
    acc[i] += __shfl_xor(acc[i], 32);
  }
  if (lane < 16) {
    // permuted layout: acc[i] = feature 64*((lane>>3)&1) + (i&3)*16 + 2*(lane&7) + (i>>2)
    const int base = ((lane >> 3) & 1) * 64 + ((lane & 7) << 1);
#pragma unroll
    for (int k = 0; k < 4; ++k) {
      const float2 b2 = *(const float2*)&bias[base + k * 16];
      *(float2*)&out[(size_t)n * F_OUT + base + k * 16] =
          make_float2(0.25f * acc[k] + b2.x, 0.25f * acc[k + 4] + b2.y);
    }
  }
}

// ---------------- launch -------------------------------------------------------
extern "C" void kernel_launch(void* const* d_in, const int* in_sizes, int n_in,
                              void* d_out, int out_size, void* d_ws, size_t ws_size,
                              hipStream_t stream) {
  const float* H    = (const float*)d_in[0];
  const int*   ei   = (const int*)d_in[1];
  const float* W    = (const float*)d_in[2];   // [4,128,256] == [512,256]
  const float* a    = (const float*)d_in[3];   // [4,256]
  const float* bias = (const float*)d_in[4];   // [128]
  const int N = in_sizes[0] / F_IN;
  const int E = in_sizes[1] / 2;
  const int* src = ei;
  const int* dst = ei + E;

  char* ws = (char*)d_ws;
  size_t o = 0;
  auto alloc = [&](size_t bytes) -> void* {
    void* p = ws + o;
    o = (o + bytes + 255) & ~(size_t)255;
    return p;
  };
  unsigned short* Wb  = (unsigned short*)alloc((size_t)COLS * F_IN * 2);
  unsigned char*  Hq  = (unsigned char*)alloc((size_t)N * COLS);        // 25.6 MB int8
  float* ssrc = (float*)alloc((size_t)N * HEADS * sizeof(float));
  unsigned char* rec = (unsigned char*)alloc((size_t)N * 32);           // 1.6 MB packed
  int*   cnt  = (int*)alloc((size_t)N * sizeof(int));
  int*   off  = (int*)alloc(((size_t)N + 1) * sizeof(int));
  unsigned short* csr = (unsigned short*)alloc((size_t)E * sizeof(unsigned short));
  unsigned short* rank = (unsigned short*)alloc((size_t)E * sizeof(unsigned short));
  const int nb = (N + 1023) / 1024;
  int*   bsum = (int*)alloc((size_t)nb * sizeof(int));

  hipMemsetAsync(cnt, 0, (size_t)N * sizeof(int), stream);

  k_wcast<<<128, 256, 0, stream>>>(W, Wb);
  k_rank<<<1024, 256, 0, stream>>>(src, cnt, rank, E);
  const int nb128 = (N + 127) / 128;
  k_gemm_q<<<4 * nb128, 256, 0, stream>>>(H, Wb, Hq, rec, ssrc, a, N);
  k_scan1<<<nb, 1024, 0, stream>>>(cnt, bsum, N);
  k_scan3<<<nb, 1024, 0, stream>>>(cnt, bsum, off, N, nb);
  k_scatter<<<1024, 256, 0, stream>>>(src, dst, off, rank, csr, E);
  k_spmm<<<(N + 3) / 4, 256, 0, stream>>>((const uint2*)Hq, (const float4*)ssrc,
                                          rec, off, csr, bias, (float*)d_out, N);
}

// Round 10
// 289.634 us; speedup vs baseline: 1.0404x; 1.0404x over previous
//
#include <hip/hip_runtime.h>

#define ALPHA 0.2f
#define EPS 1e-16f

static constexpr int F_IN = 256;
static constexpr int F_OUT = 128;
static constexpr int HEADS = 4;
static constexpr int COLS = HEADS * F_OUT; // 512

typedef __bf16 bf16x8 __attribute__((ext_vector_type(8)));
typedef float f32x4 __attribute__((ext_vector_type(4)));

static __device__ __forceinline__ unsigned short f2bf(float f) {
  unsigned int u = __float_as_uint(f);
  unsigned int r = (u + 0x7FFFu + ((u >> 16) & 1u)) >> 16;  // RN-even
  return (unsigned short)r;
}
static __device__ __forceinline__ float bf_lo(unsigned int u) {
  return __uint_as_float(u << 16);
}
static __device__ __forceinline__ float bf_hi(unsigned int u) {
  return __uint_as_float(u & 0xFFFF0000u);
}

// ---------------- K2: 128x128 MFMA GEMM (f32 A and W, cast-in-staging) --------
// Blocks >= Tg: edge-rank side pass (hidden under gemm).
// + fused score epilogue (this block == head bx) + int8(excess-128) quant.
// rec[n] (32B): bytes 0..15 = sdst (4 f32); bytes 16..31 = 8 bf16 scales.
// Hq row layout (per 64-col block b): u32 at byte 64b+4k holds cols {0,16,32,48}+k.
__global__ __launch_bounds__(256) void k_gemm_q(const float* __restrict__ A,
                                                const float* __restrict__ Wf,
                                                unsigned char* __restrict__ Hq,
                                                unsigned char* __restrict__ rec,
                                                float* __restrict__ ssrc,
                                                const float* __restrict__ Av, int N, int Tg,
                                                const int* __restrict__ src,
                                                int* __restrict__ cnt,
                                                unsigned short* __restrict__ rank, int E) {
  if ((int)blockIdx.x >= Tg) {   // ---- rank side-blocks (1024 blocks) ----
    int i = ((int)blockIdx.x - Tg) * 256 + threadIdx.x;
    const int stride = 1024 * 256;
    for (; i < E; i += stride) rank[i] = (unsigned short)atomicAdd(&cnt[src[i]], 1);
    return;
  }
  __shared__ __bf16 As[128][40];
  __shared__ __bf16 Bs[128][40];
  __shared__ float sS[128], sD[128];
  // --- bijective XCD chunking over the Tg gemm blocks (col-fastest) ---
  const int T = Tg;
  const int q8 = T >> 3, r8 = T & 7;
  const int xcd = blockIdx.x & 7, ii = blockIdx.x >> 3;
  const int gp = (xcd < r8) ? xcd * (q8 + 1) + ii
                            : r8 * (q8 + 1) + (xcd - r8) * q8 + ii;
  const int by = gp >> 2;                  // row-tile
  const int bx = gp & 3;                   // 128-col block == head
  const int t = threadIdx.x;
  const int w = t >> 6, l = t & 63;
  const int wr = w >> 1, wc = w & 1;       // 2x2 wave grid, each 64x64
  const int m0 = by << 7, n0 = bx << 7;
  const int lr = t >> 1, seg16 = (t & 1) << 4;   // staging: row 0..127, col 0/16
  f32x4 acc[4][4] = {};
  for (int k0 = 0; k0 < F_IN; k0 += 32) {
    int ar = m0 + lr; if (ar >= N) ar = N - 1;   // clamp; stores guarded
    const float4 f0 = *(const float4*)&A[(size_t)ar * F_IN + k0 + seg16];
    const float4 f1 = *(const float4*)&A[(size_t)ar * F_IN + k0 + seg16 + 4];
    const float4 f2 = *(const float4*)&A[(size_t)ar * F_IN + k0 + seg16 + 8];
    const float4 f3 = *(const float4*)&A[(size_t)ar * F_IN + k0 + seg16 + 12];
    const float4 g0 = *(const float4*)&Wf[(size_t)(n0 + lr) * F_IN + k0 + seg16];
    const float4 g1 = *(const float4*)&Wf[(size_t)(n0 + lr) * F_IN + k0 + seg16 + 4];
    const float4 g2 = *(const float4*)&Wf[(size_t)(n0 + lr) * F_IN + k0 + seg16 + 8];
    const float4 g3 = *(const float4*)&Wf[(size_t)(n0 + lr) * F_IN + k0 + seg16 + 12];
    bf16x8 v0, v1, u0, u1;
    v0[0] = (__bf16)f0.x; v0[1] = (__bf16)f0.y; v0[2] = (__bf16)f0.z; v0[3] = (__bf16)f0.w;
    v0[4] = (__bf16)f1.x; v0[5] = (__bf16)f1.y; v0[6] = (__bf16)f1.z; v0[7] = (__bf16)f1.w;
    v1[0] = (__bf16)f2.x; v1[1] = (__bf16)f2.y; v1[2] = (__bf16)f2.z; v1[3] = (__bf16)f2.w;
    v1[4] = (__bf16)f3.x; v1[5] = (__bf16)f3.y; v1[6] = (__bf16)f3.z; v1[7] = (__bf16)f3.w;
    u0[0] = (__bf16)g0.x; u0[1] = (__bf16)g0.y; u0[2] = (__bf16)g0.z; u0[3] = (__bf16)g0.w;
    u0[4] = (__bf16)g1.x; u0[5] = (__bf16)g1.y; u0[6] = (__bf16)g1.z; u0[7] = (__bf16)g1.w;
    u1[0] = (__bf16)g2.x; u1[1] = (__bf16)g2.y; u1[2] = (__bf16)g2.z; u1[3] = (__bf16)g2.w;
    u1[4] = (__bf16)g3.x; u1[5] = (__bf16)g3.y; u1[6] = (__bf16)g3.z; u1[7] = (__bf16)g3.w;
    __syncthreads();
    *(bf16x8*)&As[lr][seg16] = v0;  *(bf16x8*)&As[lr][seg16 + 8] = v1;
    *(bf16x8*)&Bs[lr][seg16] = u0;  *(bf16x8*)&Bs[lr][seg16 + 8] = u1;
    __syncthreads();
    const int kb = (l >> 4) << 3;
    bf16x8 af[4], bf_[4];
#pragma unroll
    for (int mi = 0; mi < 4; ++mi)
      af[mi] = *(const bf16x8*)&As[(wr << 6) + (mi << 4) + (l & 15)][kb];
#pragma unroll
    for (int ni = 0; ni < 4; ++ni)
      bf_[ni] = *(const bf16x8*)&Bs[(wc << 6) + (ni << 4) + (l & 15)][kb];
#pragma unroll
    for (int mi = 0; mi < 4; ++mi)
#pragma unroll
      for (int ni = 0; ni < 4; ++ni)
        acc[mi][ni] = __builtin_amdgcn_mfma_f32_16x16x32_bf16(af[mi], bf_[ni], acc[mi][ni], 0, 0, 0);
  }
  // ---- score epilogue: s_src/s_dst for head bx from f32 accumulators ----
  {
    float as_[4], ad_[4];
#pragma unroll
    for (int ni = 0; ni < 4; ++ni) {
      const int f = (wc << 6) + (ni << 4) + (l & 15);
      as_[ni] = Av[bx * 256 + f];
      ad_[ni] = Av[bx * 256 + 128 + f];
    }
#pragma unroll
    for (int mi = 0; mi < 4; ++mi)
#pragma unroll
      for (int r = 0; r < 4; ++r) {
        float ds_ = 0.f, dd_ = 0.f;
#pragma unroll
        for (int ni = 0; ni < 4; ++ni) {
          ds_ = fmaf(acc[mi][ni][r], as_[ni], ds_);
          dd_ = fmaf(acc[mi][ni][r], ad_[ni], dd_);
        }
#pragma unroll
        for (int m = 1; m < 16; m <<= 1) {
          ds_ += __shfl_xor(ds_, m);
          dd_ += __shfl_xor(dd_, m);
        }
        if (wc == 0 && (l & 15) == 0) {
          const int rl = (wr << 6) + (mi << 4) + ((l >> 4) << 2) + r;
          sS[rl] = ds_; sD[rl] = dd_;
        }
      }
    __syncthreads();
    if (wc == 1) {
#pragma unroll
      for (int mi = 0; mi < 4; ++mi)
#pragma unroll
        for (int r = 0; r < 4; ++r) {
          float ds_ = 0.f, dd_ = 0.f;
#pragma unroll
          for (int ni = 0; ni < 4; ++ni) {
            ds_ = fmaf(acc[mi][ni][r], as_[ni], ds_);
            dd_ = fmaf(acc[mi][ni][r], ad_[ni], dd_);
          }
#pragma unroll
          for (int m = 1; m < 16; m <<= 1) {
            ds_ += __shfl_xor(ds_, m);
            dd_ += __shfl_xor(dd_, m);
          }
          if ((l & 15) == 0) {
            const int rl = (wr << 6) + (mi << 4) + ((l >> 4) << 2) + r;
            const int row = m0 + rl;
            if (row < N) {
              ssrc[row * 4 + bx] = sS[rl] + ds_;
              *(float*)&rec[(size_t)row * 32 + (bx << 2)] = sD[rl] + dd_;
            }
          }
        }
    }
  }
  // ---- quant epilogue: per-row absmax per 64-col block, excess-128 int8 ----
  const int bxg = (bx << 1) + wc;          // global 64-col block 0..7
#pragma unroll
  for (int mi = 0; mi < 4; ++mi)
#pragma unroll
    for (int r = 0; r < 4; ++r) {
      float mx = 0.f;
#pragma unroll
      for (int ni = 0; ni < 4; ++ni) mx = fmaxf(mx, fabsf(acc[mi][ni][r]));
#pragma unroll
      for (int m = 1; m < 16; m <<= 1) mx = fmaxf(mx, __shfl_xor(mx, m));
      const int row = m0 + (wr << 6) + (mi << 4) + ((l >> 4) << 2) + r;
      if (row < N) {
        const float inv = (mx > 0.f) ? 127.f / mx : 0.f;
        if ((l & 15) == 0)
          *(unsigned short*)&rec[(size_t)row * 32 + 16 + (bxg << 1)] = f2bf(mx * (1.f / 127.f));
        unsigned int pk = 0;
#pragma unroll
        for (int ni = 0; ni < 4; ++ni) {
          float tq = fminf(fmaxf(rintf(acc[mi][ni][r] * inv), -127.f), 127.f);
          pk |= ((unsigned int)(((int)tq + 128) & 255)) << (8 * ni);  // excess-128
        }
        *(unsigned int*)&Hq[(size_t)row * 512 + (bxg << 6) + ((l & 15) << 2)] = pk;
      }
    }
}

// ---------------- scans over cnt -> off ---------------------------------------
__global__ __launch_bounds__(1024) void k_scan1(int* __restrict__ cnt,
                                                int* __restrict__ bsum, int N) {
  __shared__ int ws[16];
  const int t = threadIdx.x, g = blockIdx.x * 1024 + t;
  const int lane = t & 63, w = t >> 6;
  int v = (g < N) ? cnt[g] : 0;
#pragma unroll
  for (int o = 1; o < 64; o <<= 1) {
    const int y = __shfl_up(v, o);
    if (lane >= o) v += y;
  }
  if (lane == 63) ws[w] = v;
  __syncthreads();
  if (w == 0) {
    int s = (lane < 16) ? ws[lane] : 0;
#pragma unroll
    for (int o = 1; o < 16; o <<= 1) {
      const int y = __shfl_up(s, o);
      if (lane >= o) s += y;
    }
    if (lane < 16) ws[lane] = s;
  }
  __syncthreads();
  v += (w > 0) ? ws[w - 1] : 0;
  if (g < N) cnt[g] = v;                  // in-place inclusive within chunk
  if (t == 1023) bsum[blockIdx.x] = v;
}

// fused: every block scans bsum locally (nb <= 256), then adds carry
__global__ __launch_bounds__(1024) void k_scan3(const int* __restrict__ part,
                                                const int* __restrict__ bsum,
                                                int* __restrict__ off, int N, int nb) {
  __shared__ int sbuf[256];
  const int t = threadIdx.x;
  if (t < 64) {
    int carry = 0;
    for (int base = 0; base < nb; base += 64) {
      int v = (base + t < nb) ? bsum[base + t] : 0;
#pragma unroll
      for (int o = 1; o < 64; o <<= 1) {
        const int y = __shfl_up(v, o);
        if (t >= o) v += y;
      }
      v += carry;
      if (base + t < nb) sbuf[base + t] = v;
      carry = __shfl(v, 63);
    }
  }
  __syncthreads();
  const int g = blockIdx.x * 1024 + t;
  if (g == 0) off[0] = 0;
  if (g < N) off[g + 1] = part[g] + (blockIdx.x ? sbuf[blockIdx.x - 1] : 0);
}

// ---------------- K3: scatter (no atomics; u16 dst) ---------------------------
__global__ void k_scatter(const int* __restrict__ src, const int* __restrict__ dst,
                          const int* __restrict__ off, const unsigned short* __restrict__ rank,
                          unsigned short* __restrict__ csr_dst, int E) {
  int i = blockIdx.x * blockDim.x + threadIdx.x;
  const int stride = gridDim.x * blockDim.x;
  for (; i < E; i += stride)
    csr_dst[off[src[i]] + rank[i]] = (unsigned short)dst[i];
}

// ---------------- K4: fused softmax + SpMM, excess-128 int8 -------------------
__global__ __launch_bounds__(256) void k_spmm(const uint2* __restrict__ Hq2,
    const float4* __restrict__ ssrc4, const unsigned char* __restrict__ rec,
    const int* __restrict__ off, const unsigned short* __restrict__ csr_dst,
    const float* __restrict__ bias, float* __restrict__ out, int N) {
  __shared__ float wbuf[4][8][72];   // [wave][col-block][edge], w[h]*scl[d][b]
  __shared__ int   ibuf[4][64];
  const int wv = threadIdx.x >> 6;
  const int lane = threadIdx.x & 63;
  const int n = (blockIdx.x << 2) + wv;
  if (n >= N) return;                 // wave-private LDS, no barriers
  const int hg = lane >> 4;           // head of this lane
  const int b8 = lane >> 3;           // 64-col block of this lane
  const float4 ss4 = ssrc4[n];
  float den4[4] = {};
  float acc[8] = {};
  float sw = 0.f;                     // sum of this lane's scaled weights
  const int beg = off[n], end = off[n + 1];
  for (int c0 = beg; c0 < end; c0 += 64) {
    const int cnt = min(64, end - c0);
    if (lane < cnt) {                 // -------- phase A --------
      const int d = csr_dst[c0 + lane];          // coalesced u16
      ibuf[wv][lane] = d << 6;                   // row base in uint2 units
      const float4 sd4 = *(const float4*)&rec[(size_t)d * 32];       // one line:
      const uint4  sc  = *(const uint4*)&rec[(size_t)d * 32 + 16];   // sdst+scales
      float e0 = ss4.x + sd4.x; e0 = fmaxf(e0, ALPHA * e0);
      float e1 = ss4.y + sd4.y; e1 = fmaxf(e1, ALPHA * e1);
      float e2 = ss4.z + sd4.z; e2 = fmaxf(e2, ALPHA * e2);
      float e3 = ss4.w + sd4.w; e3 = fmaxf(e3, ALPHA * e3);
      const float w0 = __expf(e0), w1 = __expf(e1), w2 = __expf(e2), w3 = __expf(e3);
      den4[0] += w0; den4[1] += w1; den4[2] += w2; den4[3] += w3;
      wbuf[wv][0][lane] = w0 * bf_lo(sc.x); wbuf[wv][1][lane] = w0 * bf_hi(sc.x);
      wbuf[wv][2][lane] = w1 * bf_lo(sc.y); wbuf[wv][3][lane] = w1 * bf_hi(sc.y);
      wbuf[wv][4][lane] = w2 * bf_lo(sc.z); wbuf[wv][5][lane] = w2 * bf_hi(sc.z);
      wbuf[wv][6][lane] = w3 * bf_lo(sc.w); wbuf[wv][7][lane] = w3 * bf_hi(sc.w);
    }
#pragma unroll 8
    for (int j = 0; j < cnt; ++j) {   // -------- phase B --------
      const float wgt = wbuf[wv][b8][j];         // LDS broadcast (scaled)
      const int db = ibuf[wv][j];                // LDS broadcast
      const uint2 q = Hq2[db + lane];            // 8B gather, 512B/row/wave
      sw += wgt;
      acc[0] = fmaf(wgt, (float)(q.x & 0xffu),         acc[0]);
      acc[1] = fmaf(wgt, (float)((q.x >> 8) & 0xffu),  acc[1]);
      acc[2] = fmaf(wgt, (float)((q.x >> 16) & 0xffu), acc[2]);
      acc[3] = fmaf(wgt, (float)(q.x >> 24),           acc[3]);
      acc[4] = fmaf(wgt, (float)(q.y & 0xffu),         acc[4]);
      acc[5] = fmaf(wgt, (float)((q.y >> 8) & 0xffu),  acc[5]);
      acc[6] = fmaf(wgt, (float)((q.y >> 16) & 0xffu), acc[6]);
      acc[7] = fmaf(wgt, (float)(q.y >> 24),           acc[7]);
    }
  }
#pragma unroll
  for (int k = 0; k < 4; ++k)
#pragma unroll
    for (int m = 1; m < 64; m <<= 1) den4[k] += __shfl_xor(den4[k], m);
  const float r = 1.f / (den4[hg] + EPS);
  const float corr = 128.f * sw;      // undo excess-128 bias
#pragma unroll
  for (int i = 0; i < 8; ++i) acc[i] = (acc[i] - corr) * r;
#pragma unroll
  for (int i = 0; i < 8; ++i) {       // sum the 4 heads (same feature at l^16,l^32)
    acc[i] += __shfl_xor(acc[i], 16);
    acc[i] += __shfl_xor(acc[i], 32);
  }
  if (lane < 16) {
    // permuted layout: acc[i] = feature 64*((lane>>3)&1) + (i&3)*16 + 2*(lane&7) + (i>>2)
    const int base = ((lane >> 3) & 1) * 64 + ((lane & 7) << 1);
#pragma unroll
    for (int k = 0; k < 4; ++k) {
      const float2 b2 = *(const float2*)&bias[base + k * 16];
      *(float2*)&out[(size_t)n * F_OUT + base + k * 16] =
          make_float2(0.25f * acc[k] + b2.x, 0.25f * acc[k + 4] + b2.y);
    }
  }
}

// ---------------- launch -------------------------------------------------------
extern "C" void kernel_launch(void* const* d_in, const int* in_sizes, int n_in,
                              void* d_out, int out_size, void* d_ws, size_t ws_size,
                              hipStream_t stream) {
  const float* H    = (const float*)d_in[0];
  const int*   ei   = (const int*)d_in[1];
  const float* W    = (const float*)d_in[2];   // [4,128,256] == [512,256]
  const float* a    = (const float*)d_in[3];   // [4,256]
  const float* bias = (const float*)d_in[4];   // [128]
  const int N = in_sizes[0] / F_IN;
  const int E = in_sizes[1] / 2;
  const int* src = ei;
  const int* dst = ei + E;

  char* ws = (char*)d_ws;
  size_t o = 0;
  auto alloc = [&](size_t bytes) -> void* {
    void* p = ws + o;
    o = (o + bytes + 255) & ~(size_t)255;
    return p;
  };
  unsigned char*  Hq  = (unsigned char*)alloc((size_t)N * COLS);        // 25.6 MB int8
  float* ssrc = (float*)alloc((size_t)N * HEADS * sizeof(float));
  unsigned char* rec = (unsigned char*)alloc((size_t)N * 32);           // 1.6 MB packed
  int*   cnt  = (int*)alloc((size_t)N * sizeof(int));
  int*   off  = (int*)alloc(((size_t)N + 1) * sizeof(int));
  unsigned short* csr = (unsigned short*)alloc((size_t)E * sizeof(unsigned short));
  unsigned short* rank = (unsigned short*)alloc((size_t)E * sizeof(unsigned short));
  const int nb = (N + 1023) / 1024;
  int*   bsum = (int*)alloc((size_t)nb * sizeof(int));

  hipMemsetAsync(cnt, 0, (size_t)N * sizeof(int), stream);

  const int nb128 = (N + 127) / 128;
  const int Tg = 4 * nb128;
  k_gemm_q<<<Tg + 1024, 256, 0, stream>>>(H, W, Hq, rec, ssrc, a, N, Tg,
                                          src, cnt, rank, E);
  k_scan1<<<nb, 1024, 0, stream>>>(cnt, bsum, N);
  k_scan3<<<nb, 1024, 0, stream>>>(cnt, bsum, off, N, nb);
  k_scatter<<<1024, 256, 0, stream>>>(src, dst, off, rank, csr, E);
  k_spmm<<<(N + 3) / 4, 256, 0, stream>>>((const uint2*)Hq, (const float4*)ssrc,
                                          rec, off, csr, bias, (float*)d_out, N);
}